// Round 1
// 878.855 us; speedup vs baseline: 1.0607x; 1.0607x over previous
//
#include <hip/hip_runtime.h>

#define Vn   50000
#define NNZn 1600000
#define Bn   4
#define FINn 128
#define FOUTn 128
#define Kn   5
#define ROWF 512   // B*FIN features per vertex row
#define Mtot (Bn * Vn)
#define NSCAN 13   // ceil(V/4096)

typedef __attribute__((ext_vector_type(8))) short short8;
typedef __attribute__((ext_vector_type(4))) float f32x4;
typedef __attribute__((ext_vector_type(2))) float f32x2;
typedef long long i64v;

// ---------- bf16 helpers ----------
static __device__ __forceinline__ unsigned short f2bf(float f) {
    unsigned u = __float_as_uint(f);
    u += 0x7fffu + ((u >> 16) & 1u);   // RNE
    return (unsigned short)(u >> 16);
}
static __device__ __forceinline__ unsigned pk2(float a, float b) {
    return (unsigned)f2bf(a) | ((unsigned)f2bf(b) << 16);
}

// async global->LDS, 16B per lane; lds base must be wave-uniform, dest = base + lane*16
static __device__ __forceinline__ void gload_lds16(const void* g, void* l) {
    __builtin_amdgcn_global_load_lds((const __attribute__((address_space(1))) unsigned int*)g,
                                     (__attribute__((address_space(3))) unsigned int*)l, 16, 0, 0);
}

// ---------- prep: zero cnt + x0 transpose (+fp8 mirror) + Chebyshev-folded weight images ----------
// Powers reformulation: out = sum_j (L^j x0) W'_j with
//   W'0 = W0 - W2 + W4 ; W'1 = W1 - 3 W3 ; W'2 = 2 W2 - 8 W4 ; W'3 = 4 W3 ; W'4 = 8 W4
// (ref pairs xk axis fin*K+k with weight flat axis -> W_eff[k][fin][fo] = w.flat[(fin*K+k)*FOUT+fo])
// Weight images are stored PRE-PERMUTED in the exact LDS layout the GEMM fragment reads use:
//   img_idx = ((n*4+kc)*64 + lane)*8 + e,  fo = n*16 + (lane&15),  fin = kc*32 + (lane>>4)*8 + e
// wbfT: hops 0,1 in bf16 (2 x 32KB). wf8T: hops 2,3,4 in fp8 e4m3 (3 x 16KB), unscaled weights.
__global__ __launch_bounds__(256) void prep_kernel(const float* __restrict__ in,
                                                   unsigned short* __restrict__ x0,
                                                   unsigned char* __restrict__ x0f8,
                                                   const float* __restrict__ w,
                                                   unsigned short* __restrict__ wbfT,
                                                   unsigned char* __restrict__ wf8T,
                                                   int* __restrict__ cnt) {
    int bid = blockIdx.x;
    if (bid < 12500) {
        size_t t = (size_t)bid * 256 + threadIdx.x;      // exactly B*V*16 threads
        int f8 = (int)(t & 15);
        size_t bv = t >> 4;
        int v = (int)(bv % Vn);
        int b = (int)(bv / Vn);
        const float* src = in + bv * FINn + (size_t)f8 * 8;
        float4 s0 = *(const float4*)src;
        float4 s1 = *(const float4*)(src + 4);
        uint4 o;
        o.x = pk2(s0.x, s0.y); o.y = pk2(s0.z, s0.w);
        o.z = pk2(s1.x, s1.y); o.w = pk2(s1.z, s1.w);
        size_t doff = (size_t)v * ROWF + (size_t)b * FINn + (size_t)f8 * 8;
        *(uint4*)(x0 + doff) = o;
        int w0 = 0, w1 = 0;
        w0 = __builtin_amdgcn_cvt_pk_fp8_f32(s0.x, s0.y, w0, false);
        w0 = __builtin_amdgcn_cvt_pk_fp8_f32(s0.z, s0.w, w0, true);
        w1 = __builtin_amdgcn_cvt_pk_fp8_f32(s1.x, s1.y, w1, false);
        w1 = __builtin_amdgcn_cvt_pk_fp8_f32(s1.z, s1.w, w1, true);
        uint2 o8; o8.x = (unsigned)w0; o8.y = (unsigned)w1;
        *(uint2*)(x0f8 + doff) = o8;
    } else if (bid < 12724) {
        int t = (bid - 12500) * 256 + threadIdx.x;       // [0, 57344)
        if (t < 32768) {
            // bf16 hops 0,1 — one element per thread, permuted index r
            int j = t >> 14, r = t & 16383;
            int e = r & 7, lane = (r >> 3) & 63, kc = (r >> 9) & 3, n = r >> 11;
            int fo = n * 16 + (lane & 15);
            int fin = kc * 32 + ((lane >> 4) << 3) + e;
            const float* b = w + (size_t)(fin * Kn) * FOUTn + fo;
            float v = (j == 0) ? (b[0] - b[2 * FOUTn] + b[4 * FOUTn])
                               : (b[1 * FOUTn] - 3.f * b[3 * FOUTn]);
            wbfT[t] = f2bf(v);
        } else {
            // fp8 hops 2,3,4 — one byte-pair per thread
            int u = t - 32768;            // [0, 24576)
            int j = u >> 13;              // 0..2 -> hop j+2
            int rb = (u & 8191) * 2;      // even byte idx within 16KB image
            int e = rb & 7, lane = (rb >> 3) & 63, kc = (rb >> 9) & 3, n = rb >> 11;
            int fo = n * 16 + (lane & 15);
            int fin = kc * 32 + ((lane >> 4) << 3) + e;
            const float* b0 = w + (size_t)(fin * Kn) * FOUTn + fo;
            const float* b1 = w + (size_t)((fin + 1) * Kn) * FOUTn + fo;
            float v0, v1;
            if (j == 0)      { v0 = 2.f * b0[2 * FOUTn] - 8.f * b0[4 * FOUTn];
                               v1 = 2.f * b1[2 * FOUTn] - 8.f * b1[4 * FOUTn]; }
            else if (j == 1) { v0 = 4.f * b0[3 * FOUTn];  v1 = 4.f * b1[3 * FOUTn]; }
            else             { v0 = 8.f * b0[4 * FOUTn];  v1 = 8.f * b1[4 * FOUTn]; }
            int pk = __builtin_amdgcn_cvt_pk_fp8_f32(v0, v1, 0, false);
            *(unsigned short*)(wf8T + (size_t)j * 16384 + rb) = (unsigned short)(pk & 0xffff);
        }
    } else {
        int i = (bid - 12724) * 256 + threadIdx.x;
        if (i < Vn) cnt[i] = 0;
    }
}

// ---------- CSR build ----------
__global__ __launch_bounds__(256) void hist_kernel(const int* __restrict__ rows, int* __restrict__ cnt) {
    int e = blockIdx.x * 256 + threadIdx.x;
    if (e < NNZn) atomicAdd(&cnt[rows[e]], 1);
}

__global__ __launch_bounds__(1024) void scan_part_kernel(const int* __restrict__ cnt,
                                                         int* __restrict__ rp, int* __restrict__ bsum) {
    __shared__ int buf[1024];
    int blk = blockIdx.x, tid = threadIdx.x;
    int i0 = blk * 4096 + tid * 4;
    int x0 = 0, x1 = 0, x2 = 0, x3 = 0;
    if (i0 + 0 < Vn) x0 = cnt[i0 + 0];
    if (i0 + 1 < Vn) x1 = cnt[i0 + 1];
    if (i0 + 2 < Vn) x2 = cnt[i0 + 2];
    if (i0 + 3 < Vn) x3 = cnt[i0 + 3];
    int s = x0 + x1 + x2 + x3;
    buf[tid] = s;
    __syncthreads();
    for (int o = 1; o < 1024; o <<= 1) {
        int y = (tid >= o) ? buf[tid - o] : 0;
        __syncthreads();
        buf[tid] += y;
        __syncthreads();
    }
    int incl = buf[tid];
    int p = incl - s;
    if (i0 + 0 < Vn) { rp[i0 + 0] = p; p += x0; }
    if (i0 + 1 < Vn) { rp[i0 + 1] = p; p += x1; }
    if (i0 + 2 < Vn) { rp[i0 + 2] = p; p += x2; }
    if (i0 + 3 < Vn) { rp[i0 + 3] = p; }
    if (tid == 1023) bsum[blk] = incl;
}

__global__ __launch_bounds__(64) void scan_tot_kernel(int* __restrict__ bsum) {
    if (threadIdx.x == 0 && blockIdx.x == 0) {
        int run = 0;
        for (int b = 0; b < NSCAN; ++b) { int t = bsum[b]; bsum[b] = run; run += t; }
    }
}

__global__ __launch_bounds__(256) void scan_add_kernel(int* __restrict__ rp, int* __restrict__ cnt,
                                                       const int* __restrict__ bsum) {
    int i = blockIdx.x * 256 + threadIdx.x;
    if (i < Vn) {
        int v = rp[i] + bsum[i >> 12];
        rp[i] = v;
        cnt[i] = v;
    }
    if (i == 0) rp[Vn] = NNZn;
}

__global__ __launch_bounds__(256) void scatter_kernel(const int* __restrict__ rows, const int* __restrict__ cols,
                                                      const float* __restrict__ vals, int* __restrict__ cursor,
                                                      uint2* __restrict__ ecv) {
    int e = blockIdx.x * 256 + threadIdx.x;
    if (e < NNZn) {
        int r = rows[e];
        int p = atomicAdd(&cursor[r], 1);
        uint2 ev; ev.x = (unsigned)cols[e]; ev.y = __float_as_uint(vals[e]);
        ecv[p] = ev;
    }
}

// ---------- SPMM (powers form): a = L * gather(f8prev); write f8new = fp8(16*a) [+ optional bf16 a] ----------
// Mirrors carry scale 16^j: f8prev = 16^(j-1) y_{j-1}  =>  a = 16^(j-1) y_j, f8new = 16^j y_j.
__global__ __launch_bounds__(256) void spmm_kernel(const int* __restrict__ rp, const uint2* __restrict__ ecv,
                                                   const unsigned char* __restrict__ f8prev,
                                                   unsigned char* __restrict__ f8new,
                                                   unsigned short* __restrict__ bfout, int wbf) {
    int gw = (blockIdx.x * 256 + threadIdx.x) >> 6;
    if (gw >= Vn) return;
    int lane = threadIdx.x & 63;
    int s = rp[gw], e = rp[gw + 1];
    f32x2 a0 = {0.f, 0.f}, a1 = {0.f, 0.f}, a2 = {0.f, 0.f}, a3 = {0.f, 0.f};
    const unsigned char* gbase = f8prev + (size_t)lane * 8;

#define ACCUM(g, vf)                                                             \
    {                                                                            \
        f32x2 vv = {vf, vf};                                                     \
        f32x2 p0 = __builtin_amdgcn_cvt_pk_f32_fp8((int)(g).x, false);           \
        f32x2 p1 = __builtin_amdgcn_cvt_pk_f32_fp8((int)(g).x, true);            \
        f32x2 p2 = __builtin_amdgcn_cvt_pk_f32_fp8((int)(g).y, false);           \
        f32x2 p3 = __builtin_amdgcn_cvt_pk_f32_fp8((int)(g).y, true);            \
        a0 += p0 * vv; a1 += p1 * vv; a2 += p2 * vv; a3 += p3 * vv;              \
    }

    int i = s;
    for (; i + 4 <= e; i += 4) {
        uint2 ec0 = ecv[i], ec1 = ecv[i + 1], ec2 = ecv[i + 2], ec3 = ecv[i + 3];
        uint2 g0 = *(const uint2*)(gbase + (size_t)ec0.x * ROWF);
        uint2 g1 = *(const uint2*)(gbase + (size_t)ec1.x * ROWF);
        uint2 g2 = *(const uint2*)(gbase + (size_t)ec2.x * ROWF);
        uint2 g3 = *(const uint2*)(gbase + (size_t)ec3.x * ROWF);
        ACCUM(g0, __uint_as_float(ec0.y));
        ACCUM(g1, __uint_as_float(ec1.y));
        ACCUM(g2, __uint_as_float(ec2.y));
        ACCUM(g3, __uint_as_float(ec3.y));
    }
    for (; i < e; ++i) {
        uint2 ec0 = ecv[i];
        uint2 g0 = *(const uint2*)(gbase + (size_t)ec0.x * ROWF);
        ACCUM(g0, __uint_as_float(ec0.y));
    }
#undef ACCUM

    size_t doff = (size_t)gw * ROWF + (size_t)lane * 8;
    if (wbf) {   // unscaled bf16 y1 for the GEMM's bf16 hop
        uint4 o;
        o.x = pk2(a0.x, a0.y); o.y = pk2(a1.x, a1.y);
        o.z = pk2(a2.x, a2.y); o.w = pk2(a3.x, a3.y);
        *(uint4*)(bfout + doff) = o;
    }
    int w0 = 0, w1 = 0;
    w0 = __builtin_amdgcn_cvt_pk_fp8_f32(16.f * a0.x, 16.f * a0.y, w0, false);
    w0 = __builtin_amdgcn_cvt_pk_fp8_f32(16.f * a1.x, 16.f * a1.y, w0, true);
    w1 = __builtin_amdgcn_cvt_pk_fp8_f32(16.f * a2.x, 16.f * a2.y, w1, false);
    w1 = __builtin_amdgcn_cvt_pk_fp8_f32(16.f * a3.x, 16.f * a3.y, w1, true);
    uint2 o8; o8.x = (unsigned)w0; o8.y = (unsigned)w1;
    *(uint2*)(f8new + doff) = o8;
}

// ---------- MFMA GEMM: Horner over hops 4,3,2 (fp8, scaled 16^j) then 1,0 (bf16) ----------
// acc init = bias*65536 (exact 2^16); transitions /16, /16, /256 make every hop land at scale 1.
__global__ __launch_bounds__(256, 2) void gemm_mfma_kernel(const unsigned short* __restrict__ y0,
                                                           const unsigned short* __restrict__ y1,
                                                           const unsigned char* __restrict__ y2,
                                                           const unsigned char* __restrict__ y3,
                                                           const unsigned char* __restrict__ y4,
                                                           const unsigned short* __restrict__ wbfT,
                                                           const unsigned char* __restrict__ wf8T,
                                                           const float* __restrict__ bias,
                                                           float* __restrict__ out) {
    __shared__ __align__(16) unsigned char Wf[2][32768];   // 2 x 32KB (fp8 hops use first 16KB)
    int tid = threadIdx.x;
    int wave = tid >> 6, lane = tid & 63;
    int q = lane >> 4, mr = lane & 15;
    int m0 = blockIdx.x * 128;

    size_t aoff[2];
#pragma unroll
    for (int t = 0; t < 2; ++t) {
        int m = m0 + wave * 32 + t * 16 + mr;
        if (m > Mtot - 1) m = Mtot - 1;
        int b = m / Vn, v = m - b * Vn;
        aoff[t] = (size_t)v * ROWF + (size_t)b * FINn;   // element==byte for fp8, element==short for bf16
    }

    f32x4 acc[2][8];
#pragma unroll
    for (int n = 0; n < 8; ++n) {
        float bc = bias[n * 16 + mr] * 65536.f;
        f32x4 bi = {bc, bc, bc, bc};
        acc[0][n] = bi; acc[1][n] = bi;
    }

    i64v AfA[2][4], AfB[2][4];
    short8 AbA[2][4], AbB[2][4];

    auto stage4 = [&](const unsigned char* src, int buf) {   // 16KB linear copy
#pragma unroll
        for (int c = 0; c < 4; ++c)
            gload_lds16(src + (size_t)((c * 4 + wave) * 64 + lane) * 16,
                        &Wf[buf][(size_t)((c * 4 + wave) * 64) * 16]);
    };
    auto stage8 = [&](const unsigned short* src, int buf) {  // 32KB linear copy
#pragma unroll
        for (int c = 0; c < 8; ++c)
            gload_lds16((const unsigned char*)src + (size_t)((c * 4 + wave) * 64 + lane) * 16,
                        &Wf[buf][(size_t)((c * 4 + wave) * 64) * 16]);
    };
    auto loadAf8 = [&](i64v (&dst)[2][4], const unsigned char* src) {
#pragma unroll
        for (int t = 0; t < 2; ++t)
#pragma unroll
            for (int kc = 0; kc < 4; ++kc)
                dst[t][kc] = *(const i64v*)(src + aoff[t] + kc * 32 + q * 8);
    };
    auto loadAb = [&](short8 (&dst)[2][4], const unsigned short* src) {
#pragma unroll
        for (int t = 0; t < 2; ++t)
#pragma unroll
            for (int kc = 0; kc < 4; ++kc)
                dst[t][kc] = *(const short8*)(src + aoff[t] + kc * 32 + q * 8);
    };
    auto mmF8 = [&](int buf, i64v (&A)[2][4]) {
#pragma unroll
        for (int n = 0; n < 8; ++n)
#pragma unroll
            for (int kc = 0; kc < 4; ++kc) {
                i64v bw = *(const i64v*)(&Wf[buf][(size_t)((n * 4 + kc) * 64 + lane) * 8]);
                acc[0][n] = __builtin_amdgcn_mfma_f32_16x16x32_fp8_fp8(A[0][kc], bw, acc[0][n], 0, 0, 0);
                acc[1][n] = __builtin_amdgcn_mfma_f32_16x16x32_fp8_fp8(A[1][kc], bw, acc[1][n], 0, 0, 0);
            }
    };
    auto mmB16 = [&](int buf, short8 (&A)[2][4]) {
#pragma unroll
        for (int n = 0; n < 8; ++n)
#pragma unroll
            for (int kc = 0; kc < 4; ++kc) {
                short8 bf = *(const short8*)(&Wf[buf][(size_t)((n * 4 + kc) * 64 + lane) * 16]);
                acc[0][n] = __builtin_amdgcn_mfma_f32_16x16x32_bf16(A[0][kc], bf, acc[0][n], 0, 0, 0);
                acc[1][n] = __builtin_amdgcn_mfma_f32_16x16x32_bf16(A[1][kc], bf, acc[1][n], 0, 0, 0);
            }
    };
    auto accsc = [&](float s) {
        f32x4 sc = {s, s, s, s};
#pragma unroll
        for (int t = 0; t < 2; ++t)
#pragma unroll
            for (int n = 0; n < 8; ++n) acc[t][n] *= sc;
    };

    // prologue: hop4 W + A
    stage4(wf8T + 2 * 16384, 0);
    loadAf8(AfA, y4);
    __syncthreads();

    // hop 4 (fp8, Wf[0]) — prefetch hop3
    stage4(wf8T + 1 * 16384, 1);
    loadAf8(AfB, y3);
    mmF8(0, AfA);
#pragma unroll
    for (int t = 0; t < 2; ++t)
#pragma unroll
        for (int kc = 0; kc < 4; ++kc) AfA[t][kc] = AfB[t][kc];
    accsc(0.0625f);
    __syncthreads();

    // hop 3 (fp8, Wf[1]) — prefetch hop2
    stage4(wf8T, 0);
    loadAf8(AfB, y2);
    mmF8(1, AfA);
#pragma unroll
    for (int t = 0; t < 2; ++t)
#pragma unroll
        for (int kc = 0; kc < 4; ++kc) AfA[t][kc] = AfB[t][kc];
    accsc(0.0625f);
    __syncthreads();

    // hop 2 (fp8, Wf[0]) — prefetch hop1 (bf16)
    stage8(wbfT + 16384, 1);
    loadAb(AbA, y1);
    mmF8(0, AfA);
    accsc(0.00390625f);
    __syncthreads();

    // hop 1 (bf16, Wf[1]) — prefetch hop0
    stage8(wbfT, 0);
    loadAb(AbB, y0);
    mmB16(1, AbA);
#pragma unroll
    for (int t = 0; t < 2; ++t)
#pragma unroll
        for (int kc = 0; kc < 4; ++kc) AbA[t][kc] = AbB[t][kc];
    __syncthreads();

    // hop 0 (bf16, Wf[0])
    mmB16(0, AbA);

    // epilogue: D layout col=lane&15, row=q*4+reg
#pragma unroll
    for (int t = 0; t < 2; ++t) {
#pragma unroll
        for (int n = 0; n < 8; ++n) {
            int col = n * 16 + mr;
#pragma unroll
            for (int r = 0; r < 4; ++r) {
                int m = m0 + wave * 32 + t * 16 + q * 4 + r;
                if (m < Mtot) out[(size_t)m * FOUTn + col] = acc[t][n][r];
            }
        }
    }
}

extern "C" void kernel_launch(void* const* d_in, const int* in_sizes, int n_in,
                              void* d_out, int out_size, void* d_ws, size_t ws_size,
                              hipStream_t stream) {
    const int* lap_rows = (const int*)d_in[0];
    const int* lap_cols = (const int*)d_in[1];
    const float* lap_vals = (const float*)d_in[2];
    const float* inputs = (const float*)d_in[3];
    const float* weight = (const float*)d_in[4];
    const float* bias = (const float*)d_in[5];
    float* out = (float*)d_out;

    char* ws = (char*)d_ws;
    size_t off = 0;
    auto alloc = [&](size_t bytes) -> char* {
        char* p = ws + off;
        off += (bytes + 255) & ~(size_t)255;
        return p;
    };
    int* cnt = (int*)alloc((size_t)Vn * sizeof(int));
    int* rp = (int*)alloc((size_t)(Vn + 1) * sizeof(int));
    int* bsum = (int*)alloc((size_t)NSCAN * sizeof(int));
    uint2* ecv = (uint2*)alloc((size_t)NNZn * sizeof(uint2));
    unsigned short* xb0 = (unsigned short*)alloc((size_t)Vn * ROWF * 2);   // bf16 y0
    unsigned short* xb1 = (unsigned short*)alloc((size_t)Vn * ROWF * 2);   // bf16 y1
    unsigned char* f0 = (unsigned char*)alloc((size_t)Vn * ROWF);          // fp8 y0 (scale 1)
    unsigned char* f1 = (unsigned char*)alloc((size_t)Vn * ROWF);          // fp8 16 y1
    unsigned char* f2 = (unsigned char*)alloc((size_t)Vn * ROWF);          // fp8 256 y2
    unsigned char* f3 = (unsigned char*)alloc((size_t)Vn * ROWF);          // fp8 4096 y3
    unsigned char* f4 = (unsigned char*)alloc((size_t)Vn * ROWF);          // fp8 65536 y4
    unsigned short* wbfT = (unsigned short*)alloc((size_t)2 * 16384 * 2);  // bf16 W'0,W'1 images
    unsigned char* wf8T = (unsigned char*)alloc((size_t)3 * 16384);        // fp8 W'2..W'4 images

    // prep: transpose+fp8 mirror | folded-weight images | zero cnt
    prep_kernel<<<12920, 256, 0, stream>>>(inputs, xb0, f0, weight, wbfT, wf8T, cnt);
    // CSR build
    hist_kernel<<<(NNZn + 255) / 256, 256, 0, stream>>>(lap_rows, cnt);
    scan_part_kernel<<<NSCAN, 1024, 0, stream>>>(cnt, rp, bsum);
    scan_tot_kernel<<<1, 64, 0, stream>>>(bsum);
    scan_add_kernel<<<(Vn + 255) / 256, 256, 0, stream>>>(rp, cnt, bsum);
    scatter_kernel<<<(NNZn + 255) / 256, 256, 0, stream>>>(lap_rows, lap_cols, lap_vals, cnt, ecv);

    const int spmm_blocks = (Vn * 64 + 255) / 256;
    const int gemm_blocks = (Mtot + 127) / 128;   // 1563

    // y1 = L y0 (writes bf16 y1 + fp8 16*y1)
    spmm_kernel<<<spmm_blocks, 256, 0, stream>>>(rp, ecv, f0, f1, xb1, 1);
    // y2..y4: fp8 mirror only
    spmm_kernel<<<spmm_blocks, 256, 0, stream>>>(rp, ecv, f1, f2, (unsigned short*)0, 0);
    spmm_kernel<<<spmm_blocks, 256, 0, stream>>>(rp, ecv, f2, f3, (unsigned short*)0, 0);
    spmm_kernel<<<spmm_blocks, 256, 0, stream>>>(rp, ecv, f3, f4, (unsigned short*)0, 0);
    // out = sum_j (L^j x0) W'_j + bias  (Horner-scaled mixed bf16/fp8 GEMM)
    gemm_mfma_kernel<<<gemm_blocks, 256, 0, stream>>>(xb0, xb1, f2, f3, f4, wbfT, wf8T, bias, out);
}

// Round 2
// 834.088 us; speedup vs baseline: 1.1177x; 1.0537x over previous
//
#include <hip/hip_runtime.h>

#define Vn   50000
#define NNZn 1600000
#define Bn   4
#define FINn 128
#define FOUTn 128
#define Kn   5
#define ROWF 512   // B*FIN features per vertex row
#define Mtot (Bn * Vn)
#define NSCAN 13   // ceil(V/4096)

typedef __attribute__((ext_vector_type(8))) short short8;
typedef __attribute__((ext_vector_type(4))) float f32x4;
typedef __attribute__((ext_vector_type(2))) float f32x2;
typedef long long i64v;

// ---------- bf16 helpers ----------
static __device__ __forceinline__ unsigned short f2bf(float f) {
    unsigned u = __float_as_uint(f);
    u += 0x7fffu + ((u >> 16) & 1u);   // RNE
    return (unsigned short)(u >> 16);
}
static __device__ __forceinline__ unsigned pk2(float a, float b) {
    return (unsigned)f2bf(a) | ((unsigned)f2bf(b) << 16);
}

// async global->LDS, 16B per lane; lds base must be wave-uniform, dest = base + lane*16
static __device__ __forceinline__ void gload_lds16(const void* g, void* l) {
    __builtin_amdgcn_global_load_lds((const __attribute__((address_space(1))) unsigned int*)g,
                                     (__attribute__((address_space(3))) unsigned int*)l, 16, 0, 0);
}

// ---------- prep: zero cnt + x0 transpose (+fp8 mirror) + Chebyshev-folded weight images ----------
// Powers reformulation: out = sum_j (L^j x0) W'_j with
//   W'0 = W0 - W2 + W4 ; W'1 = W1 - 3 W3 ; W'2 = 2 W2 - 8 W4 ; W'3 = 4 W3 ; W'4 = 8 W4
// Weight images stored PRE-PERMUTED in the exact LDS layout the GEMM fragment reads use:
//   img_idx = ((n*4+kc)*64 + lane)*8 + e,  fo = n*16 + (lane&15),  fin = kc*32 + (lane>>4)*8 + e
// wbfT: hops 0,1 in bf16 (2 x 32KB). wf8T: hops 2,3,4 in fp8 e4m3 (3 x 16KB), unscaled weights.
__global__ __launch_bounds__(256) void prep_kernel(const float* __restrict__ in,
                                                   unsigned short* __restrict__ x0,
                                                   unsigned char* __restrict__ x0f8,
                                                   const float* __restrict__ w,
                                                   unsigned short* __restrict__ wbfT,
                                                   unsigned char* __restrict__ wf8T,
                                                   int* __restrict__ cnt) {
    int bid = blockIdx.x;
    if (bid < 12500) {
        size_t t = (size_t)bid * 256 + threadIdx.x;      // exactly B*V*16 threads
        int f8 = (int)(t & 15);
        size_t bv = t >> 4;
        int v = (int)(bv % Vn);
        int b = (int)(bv / Vn);
        const float* src = in + bv * FINn + (size_t)f8 * 8;
        float4 s0 = *(const float4*)src;
        float4 s1 = *(const float4*)(src + 4);
        uint4 o;
        o.x = pk2(s0.x, s0.y); o.y = pk2(s0.z, s0.w);
        o.z = pk2(s1.x, s1.y); o.w = pk2(s1.z, s1.w);
        size_t doff = (size_t)v * ROWF + (size_t)b * FINn + (size_t)f8 * 8;
        *(uint4*)(x0 + doff) = o;
        int w0 = 0, w1 = 0;
        w0 = __builtin_amdgcn_cvt_pk_fp8_f32(s0.x, s0.y, w0, false);
        w0 = __builtin_amdgcn_cvt_pk_fp8_f32(s0.z, s0.w, w0, true);
        w1 = __builtin_amdgcn_cvt_pk_fp8_f32(s1.x, s1.y, w1, false);
        w1 = __builtin_amdgcn_cvt_pk_fp8_f32(s1.z, s1.w, w1, true);
        uint2 o8; o8.x = (unsigned)w0; o8.y = (unsigned)w1;
        *(uint2*)(x0f8 + doff) = o8;
    } else if (bid < 12724) {
        int t = (bid - 12500) * 256 + threadIdx.x;       // [0, 57344)
        if (t < 32768) {
            // bf16 hops 0,1 — one element per thread, permuted index r
            int j = t >> 14, r = t & 16383;
            int e = r & 7, lane = (r >> 3) & 63, kc = (r >> 9) & 3, n = r >> 11;
            int fo = n * 16 + (lane & 15);
            int fin = kc * 32 + ((lane >> 4) << 3) + e;
            const float* b = w + (size_t)(fin * Kn) * FOUTn + fo;
            float v = (j == 0) ? (b[0] - b[2 * FOUTn] + b[4 * FOUTn])
                               : (b[1 * FOUTn] - 3.f * b[3 * FOUTn]);
            wbfT[t] = f2bf(v);
        } else {
            // fp8 hops 2,3,4 — one byte-pair per thread
            int u = t - 32768;            // [0, 24576)
            int j = u >> 13;              // 0..2 -> hop j+2
            int rb = (u & 8191) * 2;      // even byte idx within 16KB image
            int e = rb & 7, lane = (rb >> 3) & 63, kc = (rb >> 9) & 3, n = rb >> 11;
            int fo = n * 16 + (lane & 15);
            int fin = kc * 32 + ((lane >> 4) << 3) + e;
            const float* b0 = w + (size_t)(fin * Kn) * FOUTn + fo;
            const float* b1 = w + (size_t)((fin + 1) * Kn) * FOUTn + fo;
            float v0, v1;
            if (j == 0)      { v0 = 2.f * b0[2 * FOUTn] - 8.f * b0[4 * FOUTn];
                               v1 = 2.f * b1[2 * FOUTn] - 8.f * b1[4 * FOUTn]; }
            else if (j == 1) { v0 = 4.f * b0[3 * FOUTn];  v1 = 4.f * b1[3 * FOUTn]; }
            else             { v0 = 8.f * b0[4 * FOUTn];  v1 = 8.f * b1[4 * FOUTn]; }
            int pk = __builtin_amdgcn_cvt_pk_fp8_f32(v0, v1, 0, false);
            *(unsigned short*)(wf8T + (size_t)j * 16384 + rb) = (unsigned short)(pk & 0xffff);
        }
    } else {
        int i = (bid - 12724) * 256 + threadIdx.x;
        if (i < Vn) cnt[i] = 0;
    }
}

// ---------- CSR build ----------
__global__ __launch_bounds__(256) void hist_kernel(const int* __restrict__ rows, int* __restrict__ cnt) {
    int e = blockIdx.x * 256 + threadIdx.x;
    if (e < NNZn) atomicAdd(&cnt[rows[e]], 1);
}

__global__ __launch_bounds__(1024) void scan_part_kernel(const int* __restrict__ cnt,
                                                         int* __restrict__ rp, int* __restrict__ bsum) {
    __shared__ int buf[1024];
    int blk = blockIdx.x, tid = threadIdx.x;
    int i0 = blk * 4096 + tid * 4;
    int x0 = 0, x1 = 0, x2 = 0, x3 = 0;
    if (i0 + 0 < Vn) x0 = cnt[i0 + 0];
    if (i0 + 1 < Vn) x1 = cnt[i0 + 1];
    if (i0 + 2 < Vn) x2 = cnt[i0 + 2];
    if (i0 + 3 < Vn) x3 = cnt[i0 + 3];
    int s = x0 + x1 + x2 + x3;
    buf[tid] = s;
    __syncthreads();
    for (int o = 1; o < 1024; o <<= 1) {
        int y = (tid >= o) ? buf[tid - o] : 0;
        __syncthreads();
        buf[tid] += y;
        __syncthreads();
    }
    int incl = buf[tid];
    int p = incl - s;
    if (i0 + 0 < Vn) { rp[i0 + 0] = p; p += x0; }
    if (i0 + 1 < Vn) { rp[i0 + 1] = p; p += x1; }
    if (i0 + 2 < Vn) { rp[i0 + 2] = p; p += x2; }
    if (i0 + 3 < Vn) { rp[i0 + 3] = p; }
    if (tid == 1023) bsum[blk] = incl;
}

__global__ __launch_bounds__(64) void scan_tot_kernel(int* __restrict__ bsum) {
    if (threadIdx.x == 0 && blockIdx.x == 0) {
        int run = 0;
        for (int b = 0; b < NSCAN; ++b) { int t = bsum[b]; bsum[b] = run; run += t; }
    }
}

__global__ __launch_bounds__(256) void scan_add_kernel(int* __restrict__ rp, int* __restrict__ cnt,
                                                       const int* __restrict__ bsum) {
    int i = blockIdx.x * 256 + threadIdx.x;
    if (i < Vn) {
        int v = rp[i] + bsum[i >> 12];
        rp[i] = v;
        cnt[i] = v;
    }
    if (i == 0) rp[Vn] = NNZn;
}

// ---------- scatter, XCD-partitioned by row range ----------
// Problem fixed here: ecv stores land at CSR positions whose lines would otherwise be
// partially written from all 8 XCDs (non-coherent L2s) -> each 8B store evicted as its
// own 64B partial line = 101 MB HBM writes. Partition rows into 8 contiguous ranges and
// let blockIdx&7 (round-robin XCD mapping) own one range: all stores to a given ecv line
// then come from one XCD, accumulate in its L2, and evict as full lines (~12.8 MB).
// Correct regardless of the actual block->XCD mapping (each edge processed exactly once).
#define SC_EPT 4          // edges per thread
#define SC_CHUNK (256 * SC_EPT)
#define SC_NCHUNK ((NNZn + SC_CHUNK - 1) / SC_CHUNK)   // 1563
__global__ __launch_bounds__(256) void scatter_kernel(const int* __restrict__ rows, const int* __restrict__ cols,
                                                      const float* __restrict__ vals, int* __restrict__ cursor,
                                                      uint2* __restrict__ ecv) {
    int part = blockIdx.x & 7;
    int chunk = blockIdx.x >> 3;
    int lo = part * (Vn / 8), hi = lo + (Vn / 8);
    int e0 = chunk * SC_CHUNK + threadIdx.x * SC_EPT;
    if (e0 >= NNZn) return;                  // NNZ % 4 == 0, so int4 load below is safe
    int4 r4 = *(const int4*)(rows + e0);
    int rr[SC_EPT] = {r4.x, r4.y, r4.z, r4.w};
#pragma unroll
    for (int t = 0; t < SC_EPT; ++t) {
        int r = rr[t];
        if (r >= lo && r < hi) {
            int e = e0 + t;
            int p = atomicAdd(&cursor[r], 1);
            uint2 ev; ev.x = (unsigned)cols[e]; ev.y = __float_as_uint(vals[e]);
            ecv[p] = ev;
        }
    }
}

// ---------- SPMM (powers form): a = L * gather(f8prev); write f8new = fp8(16*a) [+ optional bf16 a] ----------
// Mirrors carry scale 16^j: f8prev = 16^(j-1) y_{j-1}  =>  a = 16^(j-1) y_j, f8new = 16^j y_j.
__global__ __launch_bounds__(256) void spmm_kernel(const int* __restrict__ rp, const uint2* __restrict__ ecv,
                                                   const unsigned char* __restrict__ f8prev,
                                                   unsigned char* __restrict__ f8new,
                                                   unsigned short* __restrict__ bfout, int wbf) {
    int gw = (blockIdx.x * 256 + threadIdx.x) >> 6;
    if (gw >= Vn) return;
    int lane = threadIdx.x & 63;
    int s = rp[gw], e = rp[gw + 1];
    f32x2 a0 = {0.f, 0.f}, a1 = {0.f, 0.f}, a2 = {0.f, 0.f}, a3 = {0.f, 0.f};
    const unsigned char* gbase = f8prev + (size_t)lane * 8;

#define ACCUM(g, vf)                                                             \
    {                                                                            \
        f32x2 vv = {vf, vf};                                                     \
        f32x2 p0 = __builtin_amdgcn_cvt_pk_f32_fp8((int)(g).x, false);           \
        f32x2 p1 = __builtin_amdgcn_cvt_pk_f32_fp8((int)(g).x, true);            \
        f32x2 p2 = __builtin_amdgcn_cvt_pk_f32_fp8((int)(g).y, false);           \
        f32x2 p3 = __builtin_amdgcn_cvt_pk_f32_fp8((int)(g).y, true);            \
        a0 += p0 * vv; a1 += p1 * vv; a2 += p2 * vv; a3 += p3 * vv;              \
    }

    int i = s;
    for (; i + 4 <= e; i += 4) {
        uint2 ec0 = ecv[i], ec1 = ecv[i + 1], ec2 = ecv[i + 2], ec3 = ecv[i + 3];
        uint2 g0 = *(const uint2*)(gbase + (size_t)ec0.x * ROWF);
        uint2 g1 = *(const uint2*)(gbase + (size_t)ec1.x * ROWF);
        uint2 g2 = *(const uint2*)(gbase + (size_t)ec2.x * ROWF);
        uint2 g3 = *(const uint2*)(gbase + (size_t)ec3.x * ROWF);
        ACCUM(g0, __uint_as_float(ec0.y));
        ACCUM(g1, __uint_as_float(ec1.y));
        ACCUM(g2, __uint_as_float(ec2.y));
        ACCUM(g3, __uint_as_float(ec3.y));
    }
    for (; i < e; ++i) {
        uint2 ec0 = ecv[i];
        uint2 g0 = *(const uint2*)(gbase + (size_t)ec0.x * ROWF);
        ACCUM(g0, __uint_as_float(ec0.y));
    }
#undef ACCUM

    size_t doff = (size_t)gw * ROWF + (size_t)lane * 8;
    if (wbf) {   // unscaled bf16 y1 for the GEMM's bf16 hop
        uint4 o;
        o.x = pk2(a0.x, a0.y); o.y = pk2(a1.x, a1.y);
        o.z = pk2(a2.x, a2.y); o.w = pk2(a3.x, a3.y);
        *(uint4*)(bfout + doff) = o;
    }
    int w0 = 0, w1 = 0;
    w0 = __builtin_amdgcn_cvt_pk_fp8_f32(16.f * a0.x, 16.f * a0.y, w0, false);
    w0 = __builtin_amdgcn_cvt_pk_fp8_f32(16.f * a1.x, 16.f * a1.y, w0, true);
    w1 = __builtin_amdgcn_cvt_pk_fp8_f32(16.f * a2.x, 16.f * a2.y, w1, false);
    w1 = __builtin_amdgcn_cvt_pk_fp8_f32(16.f * a3.x, 16.f * a3.y, w1, true);
    uint2 o8; o8.x = (unsigned)w0; o8.y = (unsigned)w1;
    *(uint2*)(f8new + doff) = o8;
}

// ---------- MFMA GEMM: Horner over hops 4,3,2 (fp8, scaled 16^j) then 1,0 (bf16) ----------
// acc init = bias*65536 (exact 2^16); transitions /16, /16, /256 make every hop land at scale 1.
__global__ __launch_bounds__(256, 2) void gemm_mfma_kernel(const unsigned short* __restrict__ y0,
                                                           const unsigned short* __restrict__ y1,
                                                           const unsigned char* __restrict__ y2,
                                                           const unsigned char* __restrict__ y3,
                                                           const unsigned char* __restrict__ y4,
                                                           const unsigned short* __restrict__ wbfT,
                                                           const unsigned char* __restrict__ wf8T,
                                                           const float* __restrict__ bias,
                                                           float* __restrict__ out) {
    __shared__ __align__(16) unsigned char Wf[2][32768];   // 2 x 32KB (fp8 hops use first 16KB)
    int tid = threadIdx.x;
    int wave = tid >> 6, lane = tid & 63;
    int q = lane >> 4, mr = lane & 15;
    int m0 = blockIdx.x * 128;

    size_t aoff[2];
#pragma unroll
    for (int t = 0; t < 2; ++t) {
        int m = m0 + wave * 32 + t * 16 + mr;
        if (m > Mtot - 1) m = Mtot - 1;
        int b = m / Vn, v = m - b * Vn;
        aoff[t] = (size_t)v * ROWF + (size_t)b * FINn;   // element==byte for fp8, element==short for bf16
    }

    f32x4 acc[2][8];
#pragma unroll
    for (int n = 0; n < 8; ++n) {
        float bc = bias[n * 16 + mr] * 65536.f;
        f32x4 bi = {bc, bc, bc, bc};
        acc[0][n] = bi; acc[1][n] = bi;
    }

    i64v AfA[2][4], AfB[2][4];
    short8 AbA[2][4], AbB[2][4];

    auto stage4 = [&](const unsigned char* src, int buf) {   // 16KB linear copy
#pragma unroll
        for (int c = 0; c < 4; ++c)
            gload_lds16(src + (size_t)((c * 4 + wave) * 64 + lane) * 16,
                        &Wf[buf][(size_t)((c * 4 + wave) * 64) * 16]);
    };
    auto stage8 = [&](const unsigned short* src, int buf) {  // 32KB linear copy
#pragma unroll
        for (int c = 0; c < 8; ++c)
            gload_lds16((const unsigned char*)src + (size_t)((c * 4 + wave) * 64 + lane) * 16,
                        &Wf[buf][(size_t)((c * 4 + wave) * 64) * 16]);
    };
    auto loadAf8 = [&](i64v (&dst)[2][4], const unsigned char* src) {
#pragma unroll
        for (int t = 0; t < 2; ++t)
#pragma unroll
            for (int kc = 0; kc < 4; ++kc)
                dst[t][kc] = *(const i64v*)(src + aoff[t] + kc * 32 + q * 8);
    };
    auto loadAb = [&](short8 (&dst)[2][4], const unsigned short* src) {
#pragma unroll
        for (int t = 0; t < 2; ++t)
#pragma unroll
            for (int kc = 0; kc < 4; ++kc)
                dst[t][kc] = *(const short8*)(src + aoff[t] + kc * 32 + q * 8);
    };
    auto mmF8 = [&](int buf, i64v (&A)[2][4]) {
#pragma unroll
        for (int n = 0; n < 8; ++n)
#pragma unroll
            for (int kc = 0; kc < 4; ++kc) {
                i64v bw = *(const i64v*)(&Wf[buf][(size_t)((n * 4 + kc) * 64 + lane) * 8]);
                acc[0][n] = __builtin_amdgcn_mfma_f32_16x16x32_fp8_fp8(A[0][kc], bw, acc[0][n], 0, 0, 0);
                acc[1][n] = __builtin_amdgcn_mfma_f32_16x16x32_fp8_fp8(A[1][kc], bw, acc[1][n], 0, 0, 0);
            }
    };
    auto mmB16 = [&](int buf, short8 (&A)[2][4]) {
#pragma unroll
        for (int n = 0; n < 8; ++n)
#pragma unroll
            for (int kc = 0; kc < 4; ++kc) {
                short8 bf = *(const short8*)(&Wf[buf][(size_t)((n * 4 + kc) * 64 + lane) * 16]);
                acc[0][n] = __builtin_amdgcn_mfma_f32_16x16x32_bf16(A[0][kc], bf, acc[0][n], 0, 0, 0);
                acc[1][n] = __builtin_amdgcn_mfma_f32_16x16x32_bf16(A[1][kc], bf, acc[1][n], 0, 0, 0);
            }
    };
    auto accsc = [&](float s) {
        f32x4 sc = {s, s, s, s};
#pragma unroll
        for (int t = 0; t < 2; ++t)
#pragma unroll
            for (int n = 0; n < 8; ++n) acc[t][n] *= sc;
    };

    // prologue: hop4 W + A
    stage4(wf8T + 2 * 16384, 0);
    loadAf8(AfA, y4);
    __syncthreads();

    // hop 4 (fp8, Wf[0]) — prefetch hop3
    stage4(wf8T + 1 * 16384, 1);
    loadAf8(AfB, y3);
    mmF8(0, AfA);
#pragma unroll
    for (int t = 0; t < 2; ++t)
#pragma unroll
        for (int kc = 0; kc < 4; ++kc) AfA[t][kc] = AfB[t][kc];
    accsc(0.0625f);
    __syncthreads();

    // hop 3 (fp8, Wf[1]) — prefetch hop2
    stage4(wf8T, 0);
    loadAf8(AfB, y2);
    mmF8(1, AfA);
#pragma unroll
    for (int t = 0; t < 2; ++t)
#pragma unroll
        for (int kc = 0; kc < 4; ++kc) AfA[t][kc] = AfB[t][kc];
    accsc(0.0625f);
    __syncthreads();

    // hop 2 (fp8, Wf[0]) — prefetch hop1 (bf16)
    stage8(wbfT + 16384, 1);
    loadAb(AbA, y1);
    mmF8(0, AfA);
    accsc(0.00390625f);
    __syncthreads();

    // hop 1 (bf16, Wf[1]) — prefetch hop0
    stage8(wbfT, 0);
    loadAb(AbB, y0);
    mmB16(1, AbA);
#pragma unroll
    for (int t = 0; t < 2; ++t)
#pragma unroll
        for (int kc = 0; kc < 4; ++kc) AbA[t][kc] = AbB[t][kc];
    __syncthreads();

    // hop 0 (bf16, Wf[0])
    mmB16(0, AbA);

    // epilogue: D layout col=lane&15, row=q*4+reg
#pragma unroll
    for (int t = 0; t < 2; ++t) {
#pragma unroll
        for (int n = 0; n < 8; ++n) {
            int col = n * 16 + mr;
#pragma unroll
            for (int r = 0; r < 4; ++r) {
                int m = m0 + wave * 32 + t * 16 + q * 4 + r;
                if (m < Mtot) out[(size_t)m * FOUTn + col] = acc[t][n][r];
            }
        }
    }
}

extern "C" void kernel_launch(void* const* d_in, const int* in_sizes, int n_in,
                              void* d_out, int out_size, void* d_ws, size_t ws_size,
                              hipStream_t stream) {
    const int* lap_rows = (const int*)d_in[0];
    const int* lap_cols = (const int*)d_in[1];
    const float* lap_vals = (const float*)d_in[2];
    const float* inputs = (const float*)d_in[3];
    const float* weight = (const float*)d_in[4];
    const float* bias = (const float*)d_in[5];
    float* out = (float*)d_out;

    char* ws = (char*)d_ws;
    size_t off = 0;
    auto alloc = [&](size_t bytes) -> char* {
        char* p = ws + off;
        off += (bytes + 255) & ~(size_t)255;
        return p;
    };
    int* cnt = (int*)alloc((size_t)Vn * sizeof(int));
    int* rp = (int*)alloc((size_t)(Vn + 1) * sizeof(int));
    int* bsum = (int*)alloc((size_t)NSCAN * sizeof(int));
    uint2* ecv = (uint2*)alloc((size_t)NNZn * sizeof(uint2));
    unsigned short* xb0 = (unsigned short*)alloc((size_t)Vn * ROWF * 2);   // bf16 y0
    unsigned short* xb1 = (unsigned short*)alloc((size_t)Vn * ROWF * 2);   // bf16 y1
    unsigned char* f0 = (unsigned char*)alloc((size_t)Vn * ROWF);          // fp8 y0 (scale 1)
    unsigned char* f1 = (unsigned char*)alloc((size_t)Vn * ROWF);          // fp8 16 y1
    unsigned char* f2 = (unsigned char*)alloc((size_t)Vn * ROWF);          // fp8 256 y2
    unsigned char* f3 = (unsigned char*)alloc((size_t)Vn * ROWF);          // fp8 4096 y3
    unsigned char* f4 = (unsigned char*)alloc((size_t)Vn * ROWF);          // fp8 65536 y4
    unsigned short* wbfT = (unsigned short*)alloc((size_t)2 * 16384 * 2);  // bf16 W'0,W'1 images
    unsigned char* wf8T = (unsigned char*)alloc((size_t)3 * 16384);        // fp8 W'2..W'4 images

    // prep: transpose+fp8 mirror | folded-weight images | zero cnt
    prep_kernel<<<12920, 256, 0, stream>>>(inputs, xb0, f0, weight, wbfT, wf8T, cnt);
    // CSR build
    hist_kernel<<<(NNZn + 255) / 256, 256, 0, stream>>>(lap_rows, cnt);
    scan_part_kernel<<<NSCAN, 1024, 0, stream>>>(cnt, rp, bsum);
    scan_tot_kernel<<<1, 64, 0, stream>>>(bsum);
    scan_add_kernel<<<(Vn + 255) / 256, 256, 0, stream>>>(rp, cnt, bsum);
    // XCD-partitioned scatter: 8 row-range parts x 1563 chunks
    scatter_kernel<<<SC_NCHUNK * 8, 256, 0, stream>>>(lap_rows, lap_cols, lap_vals, cnt, ecv);

    const int spmm_blocks = (Vn * 64 + 255) / 256;
    const int gemm_blocks = (Mtot + 127) / 128;   // 1563

    // y1 = L y0 (writes bf16 y1 + fp8 16*y1)
    spmm_kernel<<<spmm_blocks, 256, 0, stream>>>(rp, ecv, f0, f1, xb1, 1);
    // y2..y4: fp8 mirror only
    spmm_kernel<<<spmm_blocks, 256, 0, stream>>>(rp, ecv, f1, f2, (unsigned short*)0, 0);
    spmm_kernel<<<spmm_blocks, 256, 0, stream>>>(rp, ecv, f2, f3, (unsigned short*)0, 0);
    spmm_kernel<<<spmm_blocks, 256, 0, stream>>>(rp, ecv, f3, f4, (unsigned short*)0, 0);
    // out = sum_j (L^j x0) W'_j + bias  (Horner-scaled mixed bf16/fp8 GEMM)
    gemm_mfma_kernel<<<gemm_blocks, 256, 0, stream>>>(xb0, xb1, f2, f3, f4, wbfT, wf8T, bias, out);
}